// Round 6
// baseline (94.689 us; speedup 1.0000x reference)
//
#include <hip/hip_runtime.h>
#include <hip/hip_bf16.h>

typedef __attribute__((ext_vector_type(8))) short bf16x8;
typedef __attribute__((ext_vector_type(4))) float f32x4;

#define B_ 64
#define T_ 1024
#define N_ 512

__device__ __forceinline__ short f2bf(float f) {
  return __builtin_bit_cast(short, __float2bfloat16(f));
}
__device__ __forceinline__ float bf2f(short s) {
  return __builtin_bit_cast(float, ((unsigned)(unsigned short)s) << 16);
}

// Reg-staged slab: 32 k x 128 n. Thread t: npair = t&63 (cols 2np,2np+1),
// kc = t>>6 (wave) -> k-rows kc*8..kc*8+7. 8x dwordx2, 512B/instr coalesced.
struct SlabRegs { float2 v[8]; };

__device__ __forceinline__ void slab_load(const float* __restrict__ Xb, int kb,
                                          int pbase, int npair, int w,
                                          SlabRegs& s) {
  const float* base = Xb + (size_t)(kb + w * 8) * N_ + pbase + npair * 2;
  #pragma unroll
  for (int j = 0; j < 8; ++j)
    s.v[j] = *(const float2*)(base + (size_t)j * N_);
}

// LDS image identical to proven r2/r4 layout: elem = row*32 + chunk*8 + sub,
// chunk cc = kc ^ ((row>>1)&3). Here (row>>1)&3 == npair&3 for both cols.
// Write = 2x ds_write_b128 full chunks: 2-way bank pattern (free, m136).
// Also accumulates per-column sum/sumsq of bf16-ROUNDED values.
__device__ __forceinline__ void slab_write(short* lds, int npair, int w,
                                           const SlabRegs& s,
                                           float (&st)[2], float (&qt)[2]) {
  const int cc = w ^ (npair & 3);
  #pragma unroll
  for (int c = 0; c < 2; ++c) {
    const int row = npair * 2 + c;
    bf16x8 pk;
    #pragma unroll
    for (int j = 0; j < 8; ++j) {
      const float f = (c == 0) ? s.v[j].x : s.v[j].y;
      pk[j] = f2bf(f);
      const float fv = bf2f(pk[j]);
      st[c] += fv; qt[c] += fv * fv;
    }
    *(bf16x8*)&lds[row * 32 + cc * 8] = pk;
  }
}

__device__ __forceinline__ void compute_step(
    const short* A, const short* Bm, int aoff, int boff, int swz,
    f32x4 (&acc)[4][4])
{
  bf16x8 af[4], bfv[4];
  #pragma unroll
  for (int mi = 0; mi < 4; ++mi) af[mi] = *(const bf16x8*)&A[aoff + mi*512 + swz];
  #pragma unroll
  for (int ni = 0; ni < 4; ++ni) bfv[ni] = *(const bf16x8*)&Bm[boff + ni*512 + swz];
  __builtin_amdgcn_s_setprio(1);
  #pragma unroll
  for (int mi = 0; mi < 4; ++mi)
    #pragma unroll
    for (int ni = 0; ni < 4; ++ni)
      acc[mi][ni] = __builtin_amdgcn_mfma_f32_16x16x32_bf16(
          af[mi], bfv[ni], acc[mi][ni], 0, 0, 0);
  __builtin_amdgcn_s_setprio(0);
}

// One block per upper-tri 128x128 tile (10/batch x 64 batches = 640 blocks).
// Reads raw fp32 X, converts+transposes in-register, stats inline, no ws.
__global__ __launch_bounds__(256, 3) void k_fused(
    const float* __restrict__ X, float* __restrict__ out)
{
  __shared__ __align__(16) short lds[2][2][4096];   // [buf][A/B] 32 KB
  __shared__ float sMu[256], sId[256];              // A:0-127, B:128-255

  const int bid = (blockIdx.x & 7) * 80 + (blockIdx.x >> 3);  // 8 XCD x 80
  const int b = bid / 10;
  const int t = bid - b * 10;
  const int ip = (t >= 4) + (t >= 7) + (t >= 9);
  const int jp = ip + t - ((ip * (9 - ip)) >> 1);
  const int rowBase = ip * 128, colBase = jp * 128;
  const bool diag = (ip == jp);

  const int tid = threadIdx.x, lane = tid & 63, wave = tid >> 6;
  const int wr = wave >> 1, wc = wave & 1;
  const int fr = lane & 15, kc = lane >> 4;
  const int swz  = (kc ^ ((fr >> 1) & 3)) * 8;
  const int aoff = (wr * 64 + fr) * 32;
  const int boff = (wc * 64 + fr) * 32;
  const int npair = tid & 63, w = tid >> 6;
  const float* Xb = X + (size_t)b * T_ * N_;

  float sA[2] = {0,0}, qA[2] = {0,0};
  float sB[2] = {0,0}, qB[2] = {0,0};
  f32x4 acc[4][4] = {};

  SlabRegs ra, rb;
  slab_load(Xb, 0, rowBase, npair, w, ra);
  if (!diag) slab_load(Xb, 0, colBase, npair, w, rb);
  slab_write(lds[0][0], npair, w, ra, sA, qA);
  if (!diag) slab_write(lds[0][1], npair, w, rb, sB, qB);
  __syncthreads();

  int cur = 0;
  #pragma unroll 1
  for (int kt = 0; kt < 32; ++kt) {
    if (kt < 31) {                                  // issue loads early (T14)
      slab_load(Xb, (kt + 1) * 32, rowBase, npair, w, ra);
      if (!diag) slab_load(Xb, (kt + 1) * 32, colBase, npair, w, rb);
    }
    compute_step(lds[cur][0], diag ? lds[cur][0] : lds[cur][1],
                 aoff, boff, swz, acc);
    if (kt < 31) {                                  // write after compute
      slab_write(lds[cur ^ 1][0], npair, w, ra, sA, qA);
      if (!diag) slab_write(lds[cur ^ 1][1], npair, w, rb, sB, qB);
    }
    __syncthreads();
    cur ^= 1;
  }

  // ---- stats block-reduce across the 4 kc-waves (reuse staging LDS) ----
  float* fb = (float*)&lds[0][0][0];   // need 2048 floats, have 8192
  #pragma unroll
  for (int c = 0; c < 2; ++c) {
    const int col = npair * 2 + c;
    fb[       0 * 512 + col * 4 + w] = sA[c];
    fb[1024 + 0 * 512 + col * 4 + w] = qA[c];
    fb[       1 * 512 + col * 4 + w] = sB[c];
    fb[1024 + 1 * 512 + col * 4 + w] = qB[c];
  }
  __syncthreads();
  {
    const int pan = tid >> 7, col = tid & 127;
    float rs = 0.f, ss = 0.f;
    #pragma unroll
    for (int k = 0; k < 4; ++k) {
      rs += fb[       pan * 512 + col * 4 + k];
      ss += fb[1024 + pan * 512 + col * 4 + k];
    }
    sMu[tid] = rs * (1.f / 32.f);                   // rs / sqrt(T)
    sId[tid] = rsqrtf(fmaxf(ss - rs * rs * (1.f / 1024.f), 1e-20f));
  }
  __syncthreads();

  // ---- epilogue. C/D map: col = lane&15, row = (lane>>4)*4 + reg ----
  const int jb = diag ? 0 : 128;
  const int jl = wc * 64 + fr;
  float aj[4], dj[4];
  #pragma unroll
  for (int ni = 0; ni < 4; ++ni) {
    aj[ni] = sMu[jb + jl + ni * 16];
    dj[ni] = sId[jb + jl + ni * 16];
  }
  #pragma unroll
  for (int mi = 0; mi < 4; ++mi) {
    const int il = wr * 64 + mi * 16 + kc * 4;
    float ai[4], di[4];
    #pragma unroll
    for (int r = 0; r < 4; ++r) { ai[r] = sMu[il + r]; di[r] = sId[il + r]; }
    #pragma unroll
    for (int ni = 0; ni < 4; ++ni) {
      f32x4 g;
      #pragma unroll
      for (int r = 0; r < 4; ++r) {
        float v = (acc[mi][ni][r] - ai[r] * aj[ni]) * (di[r] * dj[ni]);
        g[r] = fminf(fmaxf(v, -1.f), 1.f);
      }
      const int J = colBase + jl + ni * 16;
      #pragma unroll
      for (int r = 0; r < 4; ++r)
        out[((size_t)b * N_ + rowBase + il + r) * N_ + J] = g[r];   // tile
      if (!diag)
        *(f32x4*)&out[((size_t)b * N_ + J) * N_ + rowBase + il] = g; // mirror
    }
  }
}

extern "C" void kernel_launch(void* const* d_in, const int* in_sizes, int n_in,
                              void* d_out, int out_size, void* d_ws, size_t ws_size,
                              hipStream_t stream) {
  const float* X = (const float*)d_in[0];
  // bn_weight / bn_bias provably cancel in the correlation output.
  float* out = (float*)d_out;
  k_fused<<<dim3(640), 256, 0, stream>>>(X, out);
}

// Round 7
// 93.610 us; speedup vs baseline: 1.0115x; 1.0115x over previous
//
#include <hip/hip_runtime.h>
#include <hip/hip_bf16.h>

typedef __attribute__((ext_vector_type(8))) short bf16x8;
typedef __attribute__((ext_vector_type(4))) float f32x4;

#define B_ 64
#define T_ 1024
#define N_ 512

// Publish LDS writes + barrier, WITHOUT draining vmcnt: in-flight global
// loads (next tile's registers) stay outstanding across the barrier.
#define LGKM_BAR() do {                                        \
    asm volatile("s_waitcnt lgkmcnt(0)" ::: "memory");         \
    __builtin_amdgcn_s_barrier();                              \
    asm volatile("" ::: "memory");                             \
  } while (0)

__device__ __forceinline__ short f2bf(float f) {
  return __builtin_bit_cast(short, __float2bfloat16(f));
}
__device__ __forceinline__ float bf2f(short s) {
  return __builtin_bit_cast(float, ((unsigned)(unsigned short)s) << 16);
}

// Reg-staged slab: 32 k x 128 n. Thread t: npair = t&63 (cols 2np,2np+1),
// w = t>>6 -> k-rows w*8..w*8+7. 8x dwordx2, 512B/instr coalesced.
struct SlabRegs { float2 v[8]; };

__device__ __forceinline__ void slab_load(const float* __restrict__ Xb, int kb,
                                          int pbase, int npair, int w,
                                          SlabRegs& s) {
  const float* base = Xb + (size_t)(kb + w * 8) * N_ + pbase + npair * 2;
  #pragma unroll
  for (int j = 0; j < 8; ++j)
    s.v[j] = *(const float2*)(base + (size_t)j * N_);
}

// LDS image: elem = row*32 + chunk*8 + sub, chunk cc = kc ^ ((row>>1)&3);
// here (row>>1)&3 == npair&3 for both cols -> write key matches read key
// (rule #21). 2x ds_write_b128 full chunks: 2-way bank pattern (free).
// Also accumulates per-column sum/sumsq of bf16-ROUNDED values. The f2bf
// use of loaded regs is where the compiler places the implicit vmcnt wait
// -> load latency is hidden under the preceding compute_step.
__device__ __forceinline__ void slab_write(short* lds, int npair, int w,
                                           const SlabRegs& s,
                                           float (&st)[2], float (&qt)[2]) {
  const int cc = w ^ (npair & 3);
  #pragma unroll
  for (int c = 0; c < 2; ++c) {
    const int row = npair * 2 + c;
    bf16x8 pk;
    #pragma unroll
    for (int j = 0; j < 8; ++j) {
      const float f = (c == 0) ? s.v[j].x : s.v[j].y;
      pk[j] = f2bf(f);
      const float fv = bf2f(pk[j]);
      st[c] += fv; qt[c] += fv * fv;
    }
    *(bf16x8*)&lds[row * 32 + cc * 8] = pk;
  }
}

__device__ __forceinline__ void compute_step(
    const short* A, const short* Bm, int aoff, int boff, int swz,
    f32x4 (&acc)[4][4])
{
  bf16x8 af[4], bfv[4];
  #pragma unroll
  for (int mi = 0; mi < 4; ++mi) af[mi] = *(const bf16x8*)&A[aoff + mi*512 + swz];
  #pragma unroll
  for (int ni = 0; ni < 4; ++ni) bfv[ni] = *(const bf16x8*)&Bm[boff + ni*512 + swz];
  __builtin_amdgcn_s_setprio(1);
  #pragma unroll
  for (int mi = 0; mi < 4; ++mi)
    #pragma unroll
    for (int ni = 0; ni < 4; ++ni)
      acc[mi][ni] = __builtin_amdgcn_mfma_f32_16x16x32_bf16(
          af[mi], bfv[ni], acc[mi][ni], 0, 0, 0);
  __builtin_amdgcn_s_setprio(0);
}

// One block per upper-tri 128x128 tile (10/batch x 64 batches = 640 blocks).
// Reads raw fp32 X, converts+transposes in-register, stats inline, no ws.
__global__ __launch_bounds__(256, 3) void k_fused(
    const float* __restrict__ X, float* __restrict__ out)
{
  __shared__ __align__(16) short lds[2][2][4096];   // [buf][A/B] 32 KB
  __shared__ float sMu[256], sId[256];              // A:0-127, B:128-255

  const int bid = (blockIdx.x & 7) * 80 + (blockIdx.x >> 3);  // 8 XCD x 80
  const int b = bid / 10;
  const int t = bid - b * 10;
  const int ip = (t >= 4) + (t >= 7) + (t >= 9);
  const int jp = ip + t - ((ip * (9 - ip)) >> 1);
  const int rowBase = ip * 128, colBase = jp * 128;
  const bool diag = (ip == jp);

  const int tid = threadIdx.x, lane = tid & 63, wave = tid >> 6;
  const int wr = wave >> 1, wc = wave & 1;
  const int fr = lane & 15, kc = lane >> 4;
  const int swz  = (kc ^ ((fr >> 1) & 3)) * 8;
  const int aoff = (wr * 64 + fr) * 32;
  const int boff = (wc * 64 + fr) * 32;
  const int npair = tid & 63, w = tid >> 6;
  const float* Xb = X + (size_t)b * T_ * N_;

  float sA[2] = {0,0}, qA[2] = {0,0};
  float sB[2] = {0,0}, qB[2] = {0,0};
  f32x4 acc[4][4] = {};

  SlabRegs ra, rb;
  slab_load(Xb, 0, rowBase, npair, w, ra);
  if (!diag) slab_load(Xb, 0, colBase, npair, w, rb);
  slab_write(lds[0][0], npair, w, ra, sA, qA);
  if (!diag) slab_write(lds[0][1], npair, w, rb, sB, qB);
  LGKM_BAR();

  int cur = 0;
  #pragma unroll 1
  for (int kt = 0; kt < 32; ++kt) {
    if (kt < 31) {                                  // issue loads; NOT waited
      slab_load(Xb, (kt + 1) * 32, rowBase, npair, w, ra);
      if (!diag) slab_load(Xb, (kt + 1) * 32, colBase, npair, w, rb);
    }
    compute_step(lds[cur][0], diag ? lds[cur][0] : lds[cur][1],
                 aoff, boff, swz, acc);
    if (kt < 31) {                                  // implicit vmcnt wait here
      slab_write(lds[cur ^ 1][0], npair, w, ra, sA, qA);
      if (!diag) slab_write(lds[cur ^ 1][1], npair, w, rb, sB, qB);
    }
    LGKM_BAR();                                     // no vmcnt drain
    cur ^= 1;
  }

  // ---- stats block-reduce across the 4 k-waves (reuse staging LDS) ----
  // step 31 read lds[1]; lds[0] was last read in step 30, sealed by its
  // barrier -> safe to overwrite after the final LGKM_BAR.
  float* fb = (float*)&lds[0][0][0];
  #pragma unroll
  for (int c = 0; c < 2; ++c) {
    const int col = npair * 2 + c;
    fb[       0 * 512 + col * 4 + w] = sA[c];
    fb[1024 + 0 * 512 + col * 4 + w] = qA[c];
    fb[       1 * 512 + col * 4 + w] = sB[c];
    fb[1024 + 1 * 512 + col * 4 + w] = qB[c];
  }
  __syncthreads();
  {
    const int pan = tid >> 7, col = tid & 127;
    float rs = 0.f, ss = 0.f;
    #pragma unroll
    for (int k = 0; k < 4; ++k) {
      rs += fb[       pan * 512 + col * 4 + k];
      ss += fb[1024 + pan * 512 + col * 4 + k];
    }
    sMu[tid] = rs * (1.f / 32.f);                   // rs / sqrt(T)
    sId[tid] = rsqrtf(fmaxf(ss - rs * rs * (1.f / 1024.f), 1e-20f));
  }
  __syncthreads();

  // ---- epilogue. C/D map: col = lane&15, row = (lane>>4)*4 + reg ----
  const int jb = diag ? 0 : 128;
  const int jl = wc * 64 + fr;
  float aj[4], dj[4];
  #pragma unroll
  for (int ni = 0; ni < 4; ++ni) {
    aj[ni] = sMu[jb + jl + ni * 16];
    dj[ni] = sId[jb + jl + ni * 16];
  }
  #pragma unroll
  for (int mi = 0; mi < 4; ++mi) {
    const int il = wr * 64 + mi * 16 + kc * 4;
    float ai[4], di[4];
    #pragma unroll
    for (int r = 0; r < 4; ++r) { ai[r] = sMu[il + r]; di[r] = sId[il + r]; }
    #pragma unroll
    for (int ni = 0; ni < 4; ++ni) {
      f32x4 g;
      #pragma unroll
      for (int r = 0; r < 4; ++r) {
        float v = (acc[mi][ni][r] - ai[r] * aj[ni]) * (di[r] * dj[ni]);
        g[r] = fminf(fmaxf(v, -1.f), 1.f);
      }
      const int J = colBase + jl + ni * 16;
      #pragma unroll
      for (int r = 0; r < 4; ++r)
        out[((size_t)b * N_ + rowBase + il + r) * N_ + J] = g[r];   // tile
      if (!diag)
        *(f32x4*)&out[((size_t)b * N_ + J) * N_ + rowBase + il] = g; // mirror
    }
  }
}

extern "C" void kernel_launch(void* const* d_in, const int* in_sizes, int n_in,
                              void* d_out, int out_size, void* d_ws, size_t ws_size,
                              hipStream_t stream) {
  const float* X = (const float*)d_in[0];
  // bn_weight / bn_bias provably cancel in the correlation output.
  float* out = (float*)d_out;
  k_fused<<<dim3(640), 256, 0, stream>>>(X, out);
}

// Round 8
// 75.251 us; speedup vs baseline: 1.2583x; 1.2440x over previous
//
#include <hip/hip_runtime.h>
#include <hip/hip_bf16.h>

typedef __attribute__((ext_vector_type(8))) short bf16x8;
typedef __attribute__((ext_vector_type(4))) short s16x4;
typedef __attribute__((ext_vector_type(4))) float f32x4;

#define B_ 64
#define T_ 1024
#define N_ 512

#define FENCE() asm volatile("" ::: "memory")
#define VMWAIT(N) asm volatile("s_waitcnt vmcnt(" #N ")" ::: "memory")
#define BAR() __builtin_amdgcn_s_barrier()

__device__ __forceinline__ void async16(const void* g, void* l) {
  __builtin_amdgcn_global_load_lds(
      (const __attribute__((address_space(1))) unsigned int*)g,
      (__attribute__((address_space(3))) unsigned int*)l, 16, 0, 0);
}

__device__ __forceinline__ short f2bf(float f) {
  return __builtin_bit_cast(short, __float2bfloat16(f));
}
__device__ __forceinline__ float bf2f(short s) {
  return __builtin_bit_cast(float, ((unsigned)(unsigned short)s) << 16);
}

// K1 (unchanged, proven ~BW-floor): per (n-strip of 64, batch): transpose
// fp32 (T,N) -> bf16 (N,T) + per-column sum/sumsq of bf16-rounded values.
__global__ __launch_bounds__(256, 4) void k_prep(
    const float* __restrict__ X, short* __restrict__ XbT,
    float* __restrict__ amu, float* __restrict__ invd)
{
  __shared__ __align__(16) short tile[64][68];
  const int b   = blockIdx.y;
  const int n0  = blockIdx.x * 64;
  const int tid = threadIdx.x;
  const int nch = tid & 15;
  const int rg  = tid >> 4;

  float s[4] = {0.f,0.f,0.f,0.f}, q[4] = {0.f,0.f,0.f,0.f};

  for (int tt = 0; tt < 16; ++tt) {
    const int t0 = tt * 64;
    #pragma unroll
    for (int i = 0; i < 4; ++i) {
      const int tr = rg + i * 16;
      const float4 v = *(const float4*)&X[((size_t)b*T_ + t0 + tr)*N_ + n0 + nch*4];
      short bb[4];
      bb[0] = f2bf(v.x); bb[1] = f2bf(v.y); bb[2] = f2bf(v.z); bb[3] = f2bf(v.w);
      #pragma unroll
      for (int c = 0; c < 4; ++c) { float f = bf2f(bb[c]); s[c] += f; q[c] += f*f; }
      s16x4 pk = { bb[0], bb[1], bb[2], bb[3] };
      *(s16x4*)&tile[tr][nch*4] = pk;
    }
    __syncthreads();
    #pragma unroll
    for (int i = 0; i < 4; ++i) {
      const int n = rg + i * 16;
      s16x4 o = { tile[nch*4+0][n], tile[nch*4+1][n],
                  tile[nch*4+2][n], tile[nch*4+3][n] };
      *(s16x4*)&XbT[((size_t)b*N_ + n0 + n)*T_ + t0 + nch*4] = o;
    }
    __syncthreads();
  }

  float* fb = (float*)&tile[0][0];
  #pragma unroll
  for (int c = 0; c < 4; ++c) { fb[tid*8 + c] = s[c]; fb[tid*8 + 4 + c] = q[c]; }
  __syncthreads();
  if (tid < 64) {
    const int qc = tid >> 2, c = tid & 3;
    float cs = 0.f, sq = 0.f;
    #pragma unroll
    for (int g = 0; g < 16; ++g) {
      cs += fb[(g*16 + qc)*8 + c];
      sq += fb[(g*16 + qc)*8 + 4 + c];
    }
    const int n = n0 + qc*4 + c;
    amu[b*N_ + n]  = cs * (1.f/32.f);
    invd[b*N_ + n] = rsqrtf(fmaxf(sq - cs*cs*(1.f/1024.f), 1e-20f));
  }
}

// 3-buffer counted-vmcnt main loop. L = gload_lds per thread per tile
// (3 off-diag: B0,B1,A; 2 diag: B0,B1 only; A-frags read from B image).
template<int L>
__device__ __forceinline__ void gram_main(
    const short* __restrict__ Xb,
    size_t ga, size_t gb0, size_t gb1,
    short (*lds)[6144], int tid, int aoff0, int boff0, f32x4 (&acc)[2][4])
{
  auto stg = [&](int bi, int kb) {
    char* base = (char*)lds[bi];
    async16(Xb + gb0 + kb, base + tid * 16);
    async16(Xb + gb1 + kb, base + (tid + 256) * 16);
    if (L == 3) async16(Xb + ga + kb, base + 8192 + tid * 16);
  };
  auto cmp = [&](int bi) {
    const short* P = lds[bi];
    bf16x8 af[2], bfv[4];
    #pragma unroll
    for (int mi = 0; mi < 2; ++mi) af[mi] = *(const bf16x8*)&P[aoff0 + mi * 512];
    #pragma unroll
    for (int ni = 0; ni < 4; ++ni) bfv[ni] = *(const bf16x8*)&P[boff0 + ni * 512];
    __builtin_amdgcn_s_setprio(1);
    #pragma unroll
    for (int mi = 0; mi < 2; ++mi)
      #pragma unroll
      for (int ni = 0; ni < 4; ++ni)
        acc[mi][ni] = __builtin_amdgcn_mfma_f32_16x16x32_bf16(
            af[mi], bfv[ni], acc[mi][ni], 0, 0, 0);
    __builtin_amdgcn_s_setprio(0);
  };

  stg(0, 0); stg(1, 32);                        // tiles 0,1 in flight
  #pragma unroll 1
  for (int it = 0; it < 10; ++it) {             // computes tiles 3it..3it+2
    stg(2, (3*it + 2) * 32);
    if constexpr (L == 3) { VMWAIT(6); } else { VMWAIT(4); }   // tile 3it done
    BAR(); FENCE();
    cmp(0);
    FENCE(); BAR();
    stg(0, (3*it + 3) * 32);
    if constexpr (L == 3) { VMWAIT(6); } else { VMWAIT(4); }
    BAR(); FENCE();
    cmp(1);
    FENCE(); BAR();
    stg(1, (3*it + 4) * 32);
    if constexpr (L == 3) { VMWAIT(6); } else { VMWAIT(4); }
    BAR(); FENCE();
    cmp(2);
    FENCE(); BAR();
  }
  // tail: tiles 30 (buf0), 31 (buf1)
  if constexpr (L == 3) { VMWAIT(3); } else { VMWAIT(2); }
  BAR(); FENCE();
  cmp(0);
  FENCE(); BAR();
  VMWAIT(0);
  BAR(); FENCE();
  cmp(1);
}

// K2: half-tiles. Block = (batch, upper-tri tile, row-half): 64x10x2 = 1280.
// Output strip: 64 rows x 128 cols; waves 2x2, each 32x64 (acc[2][4]).
__global__ __launch_bounds__(256, 4) void k_gram(
    const short* __restrict__ XbT, const float* __restrict__ amu,
    const float* __restrict__ invd, float* __restrict__ out)
{
  __shared__ __align__(16) short lds[3][6144];  // [buf]{B:128x32, A:64x32} 36 KB

  const int bid = (blockIdx.x & 7) * 160 + (blockIdx.x >> 3);  // 8 XCD x 160
  const int b = bid / 20;
  const int rem = bid - b * 20;
  const int t = rem >> 1, h = rem & 1;
  const int ip = (t >= 4) + (t >= 7) + (t >= 9);
  const int jp = ip + t - ((ip * (9 - ip)) >> 1);
  const int rowBase = ip * 128 + h * 64;        // A rows (64)
  const int colBase = jp * 128;                 // B rows (128)
  const bool diag = (ip == jp);

  const int tid = threadIdx.x, lane = tid & 63, wave = tid >> 6;
  const int wr = wave >> 1, wc = wave & 1;
  const int fr = lane & 15, kc = lane >> 4;
  const int swz = (kc ^ ((fr >> 1) & 3)) * 8;
  const short* Xb = XbT + (size_t)b * N_ * T_;

  // staging sources (XOR swizzle on global source; LDS dest linear)
  const int r0 = tid >> 2, cl = tid & 3;
  const int cg = cl ^ ((r0 >> 1) & 3);
  const size_t gb0 = (size_t)(colBase + r0)      * T_ + cg * 8;
  const size_t gb1 = (size_t)(colBase + r0 + 64) * T_ + cg * 8;
  const size_t ga  = (size_t)(rowBase + r0)      * T_ + cg * 8;  // r0<64 rows

  // fragment bases (shorts). Key (fr>>1)&3 is invariant under +64/+128 rows.
  const int aoff0 = (diag ? h * 2048 : 4096) + (wr * 32 + fr) * 32 + swz;
  const int boff0 = (wc * 64 + fr) * 32 + swz;

  f32x4 acc[2][4] = {};
  if (diag) gram_main<2>(Xb, ga, gb0, gb1, lds, tid, aoff0, boff0, acc);
  else      gram_main<3>(Xb, ga, gb0, gb1, lds, tid, aoff0, boff0, acc);

  // Epilogue. C/D map: col = lane&15, row = (lane>>4)*4 + reg.
  const int jc = colBase + wc * 64 + fr;
  float aj[4], dj[4];
  #pragma unroll
  for (int ni = 0; ni < 4; ++ni) {
    aj[ni] = amu [b*N_ + jc + ni*16];
    dj[ni] = invd[b*N_ + jc + ni*16];
  }
  #pragma unroll
  for (int mi = 0; mi < 2; ++mi) {
    const int ibase = rowBase + wr*32 + mi*16 + kc*4;
    float ai[4], di[4];
    #pragma unroll
    for (int r = 0; r < 4; ++r) {
      ai[r] = amu [b*N_ + ibase + r];
      di[r] = invd[b*N_ + ibase + r];
    }
    #pragma unroll
    for (int ni = 0; ni < 4; ++ni) {
      f32x4 g;
      #pragma unroll
      for (int r = 0; r < 4; ++r) {
        float v = (acc[mi][ni][r] - ai[r]*aj[ni]) * (di[r]*dj[ni]);
        g[r] = fminf(fmaxf(v, -1.f), 1.f);
      }
      const int J = jc + ni * 16;
      #pragma unroll
      for (int r = 0; r < 4; ++r)
        out[((size_t)b*N_ + ibase + r)*N_ + J] = g[r];       // strip (ip,jp)
      if (!diag)
        *(f32x4*)&out[((size_t)b*N_ + J)*N_ + ibase] = g;    // mirror (jp,ip)
    }
  }
}

extern "C" void kernel_launch(void* const* d_in, const int* in_sizes, int n_in,
                              void* d_out, int out_size, void* d_ws, size_t ws_size,
                              hipStream_t stream) {
  const float* X = (const float*)d_in[0];
  // bn_weight / bn_bias provably cancel in the correlation output.
  float* out = (float*)d_out;

  char* ws = (char*)d_ws;
  short* XbT  = (short*)ws;                      // 64 MiB bf16 (N,T)
  size_t off  = (size_t)B_ * N_ * T_ * sizeof(short);
  float* amu  = (float*)(ws + off);              // 128 KiB
  float* invd = amu + B_ * N_;                   // 128 KiB

  k_prep<<<dim3(N_/64, B_), 256, 0, stream>>>(X, XbT, amu, invd);
  k_gram<<<dim3(1280), 256, 0, stream>>>(XbT, amu, invd, out);
}

// Round 9
// 72.234 us; speedup vs baseline: 1.3109x; 1.0418x over previous
//
#include <hip/hip_runtime.h>
#include <hip/hip_bf16.h>

typedef __attribute__((ext_vector_type(8))) short bf16x8;
typedef __attribute__((ext_vector_type(4))) short s16x4;
typedef __attribute__((ext_vector_type(4))) float f32x4;

#define B_ 64
#define T_ 1024
#define N_ 512

#define FENCE() asm volatile("" ::: "memory")
#define VMWAIT(N) asm volatile("s_waitcnt vmcnt(" #N ")" ::: "memory")
#define LGKM0()  asm volatile("s_waitcnt lgkmcnt(0)" ::: "memory")
#define BAR() __builtin_amdgcn_s_barrier()

__device__ __forceinline__ void async16(const void* g, void* l) {
  __builtin_amdgcn_global_load_lds(
      (const __attribute__((address_space(1))) unsigned int*)g,
      (__attribute__((address_space(3))) unsigned int*)l, 16, 0, 0);
}

__device__ __forceinline__ short f2bf(float f) {
  return __builtin_bit_cast(short, __float2bfloat16(f));
}
__device__ __forceinline__ float bf2f(short s) {
  return __builtin_bit_cast(float, ((unsigned)(unsigned short)s) << 16);
}

// K1 (unchanged, ~BW-floor): transpose fp32 (T,N) -> bf16 (N,T) + stats.
__global__ __launch_bounds__(256, 4) void k_prep(
    const float* __restrict__ X, short* __restrict__ XbT,
    float* __restrict__ amu, float* __restrict__ invd)
{
  __shared__ __align__(16) short tile[64][68];
  const int b   = blockIdx.y;
  const int n0  = blockIdx.x * 64;
  const int tid = threadIdx.x;
  const int nch = tid & 15;
  const int rg  = tid >> 4;

  float s[4] = {0.f,0.f,0.f,0.f}, q[4] = {0.f,0.f,0.f,0.f};

  for (int tt = 0; tt < 16; ++tt) {
    const int t0 = tt * 64;
    #pragma unroll
    for (int i = 0; i < 4; ++i) {
      const int tr = rg + i * 16;
      const float4 v = *(const float4*)&X[((size_t)b*T_ + t0 + tr)*N_ + n0 + nch*4];
      short bb[4];
      bb[0] = f2bf(v.x); bb[1] = f2bf(v.y); bb[2] = f2bf(v.z); bb[3] = f2bf(v.w);
      #pragma unroll
      for (int c = 0; c < 4; ++c) { float f = bf2f(bb[c]); s[c] += f; q[c] += f*f; }
      s16x4 pk = { bb[0], bb[1], bb[2], bb[3] };
      *(s16x4*)&tile[tr][nch*4] = pk;
    }
    __syncthreads();
    #pragma unroll
    for (int i = 0; i < 4; ++i) {
      const int n = rg + i * 16;
      s16x4 o = { tile[nch*4+0][n], tile[nch*4+1][n],
                  tile[nch*4+2][n], tile[nch*4+3][n] };
      *(s16x4*)&XbT[((size_t)b*N_ + n0 + n)*T_ + t0 + nch*4] = o;
    }
    __syncthreads();
  }

  float* fb = (float*)&tile[0][0];
  #pragma unroll
  for (int c = 0; c < 4; ++c) { fb[tid*8 + c] = s[c]; fb[tid*8 + 4 + c] = q[c]; }
  __syncthreads();
  if (tid < 64) {
    const int qc = tid >> 2, c = tid & 3;
    float cs = 0.f, sq = 0.f;
    #pragma unroll
    for (int g = 0; g < 16; ++g) {
      cs += fb[(g*16 + qc)*8 + c];
      sq += fb[(g*16 + qc)*8 + 4 + c];
    }
    const int n = n0 + qc*4 + c;
    amu[b*N_ + n]  = cs * (1.f/32.f);
    invd[b*N_ + n] = rsqrtf(fmaxf(sq - cs*cs*(1.f/1024.f), 1e-20f));
  }
}

// K2 main loop: 3-buffer counted vmcnt + register frag prefetch (1 step
// ahead) + ONE barrier per K-step. Buffer layout per slot (16 KB): B panel
// [0,4096) shorts, A panel [4096,8192) (off-diag only; diag reads A from B).
// Step t: VMWAIT(L) certifies tile t+1 landed; BAR; stage tile t+3 into
// b[t%3] (readers of b[t%3] = frags(t), read at step t-1 and sealed by this
// wave's LGKM0 + this barrier); ds_read frags(t+1) overlapped with MFMA on
// frags(t); LGKM0 seals the reads before the next step's barrier.
template<int L>
__device__ __forceinline__ void gram_main(
    const short* __restrict__ Xb,
    size_t ga0, size_t ga1, size_t gb0, size_t gb1,
    short* lds, int tid, int aoff, int boff, f32x4 (&acc)[4][4])
{
  auto stg = [&](int c3, int kb) {
    char* base = (char*)lds + c3 * 16384;
    async16(Xb + gb0 + kb, base + tid * 16);
    async16(Xb + gb1 + kb, base + (tid + 256) * 16);
    if constexpr (L == 4) {
      async16(Xb + ga0 + kb, base + 8192 + tid * 16);
      async16(Xb + ga1 + kb, base + 8192 + (tid + 256) * 16);
    }
  };
  auto rd = [&](int c3, bf16x8 (&A)[4], bf16x8 (&B)[4]) {
    const short* P = lds + c3 * 8192;
    #pragma unroll
    for (int i = 0; i < 4; ++i) A[i] = *(const bf16x8*)&P[aoff + i * 512];
    #pragma unroll
    for (int i = 0; i < 4; ++i) B[i] = *(const bf16x8*)&P[boff + i * 512];
  };
  auto mm = [&](bf16x8 (&A)[4], bf16x8 (&B)[4]) {
    __builtin_amdgcn_s_setprio(1);
    #pragma unroll
    for (int mi = 0; mi < 4; ++mi)
      #pragma unroll
      for (int ni = 0; ni < 4; ++ni)
        acc[mi][ni] = __builtin_amdgcn_mfma_f32_16x16x32_bf16(
            A[mi], B[ni], acc[mi][ni], 0, 0, 0);
    __builtin_amdgcn_s_setprio(0);
  };
  #define WAITL() do { if constexpr (L == 4) VMWAIT(4); else VMWAIT(2); } while (0)

  bf16x8 A0[4], B0[4], A1[4], B1[4];

  stg(0, 0); stg(1, 32); stg(2, 64);            // tiles 0,1,2 in flight
  if constexpr (L == 4) VMWAIT(8); else VMWAIT(4);   // tile 0 landed
  BAR(); FENCE();
  rd(0, A0, B0);                                 // frags(0)
  LGKM0();

  int c3 = 0;                                    // t % 3
  #pragma unroll 1
  for (int t = 0; t < 28; t += 2) {
    const int c3a = (c3 == 2) ? 0 : c3 + 1;      // (t+1)%3
    const int c3b = (c3a == 2) ? 0 : c3a + 1;    // (t+2)%3
    // even step t: MFMA frags(t) [set0], prefetch frags(t+1) -> set1
    WAITL(); BAR(); FENCE();
    stg(c3, (t + 3) * 32);
    rd(c3a, A1, B1);
    mm(A0, B0);
    LGKM0();
    // odd step t+1: MFMA frags(t+1) [set1], prefetch frags(t+2) -> set0
    WAITL(); BAR(); FENCE();
    stg(c3a, (t + 4) * 32);
    rd(c3b, A0, B0);
    mm(A1, B1);
    LGKM0();
    c3 = c3b;
  }
  // t=28 (c3==1): stage tile 31; frags(29) from buf 2
  WAITL(); BAR(); FENCE();
  stg(1, 31 * 32);
  rd(2, A1, B1);
  mm(A0, B0);                                    // MFMA 28
  LGKM0();
  // t=29: frags(30) from buf 0
  WAITL(); BAR(); FENCE();
  rd(0, A0, B0);
  mm(A1, B1);                                    // MFMA 29
  LGKM0();
  // t=30: frags(31) from buf 1
  VMWAIT(0); BAR(); FENCE();
  rd(1, A1, B1);
  mm(A0, B0);                                    // MFMA 30
  // t=31
  LGKM0();
  mm(A1, B1);                                    // MFMA 31
  #undef WAITL
}

// K2: per-batch symmetric Gram, 10 upper-tri 128x128 tiles/batch.
__global__ __launch_bounds__(256, 3) void k_gram(
    const short* __restrict__ XbT, const float* __restrict__ amu,
    const float* __restrict__ invd, float* __restrict__ out)
{
  __shared__ __align__(16) short lds[3][8192];   // 48 KB: 3 x {B 8KB, A 8KB}

  const int bid = (blockIdx.x & 7) * 80 + (blockIdx.x >> 3);  // 8 XCD x 80
  const int b = bid / 10;
  const int t = bid - b * 10;
  const int ip = (t >= 4) + (t >= 7) + (t >= 9);
  const int jp = ip + t - ((ip * (9 - ip)) >> 1);
  const int rowBase = ip * 128, colBase = jp * 128;
  const bool diag = (ip == jp);

  const int tid = threadIdx.x, lane = tid & 63, wave = tid >> 6;
  const int wr = wave >> 1, wc = wave & 1;
  const short* Xb = XbT + (size_t)b * N_ * T_;

  // staging addrs: LDS linear dest; XOR swizzle applied to global source
  const int r0 = tid >> 2, cl = tid & 3;
  const int cg = cl ^ ((r0 >> 1) & 3);
  const size_t gb0 = (size_t)(colBase + r0)      * T_ + cg * 8;
  const size_t gb1 = (size_t)(colBase + r0 + 64) * T_ + cg * 8;
  const size_t ga0 = (size_t)(rowBase + r0)      * T_ + cg * 8;
  const size_t ga1 = (size_t)(rowBase + r0 + 64) * T_ + cg * 8;

  const int fr = lane & 15, kc = lane >> 4;
  const int swz  = (kc ^ ((fr >> 1) & 3)) * 8;   // fragment-read swizzle
  const int boff = (wc * 64 + fr) * 32 + swz;
  const int aoff = (diag ? 0 : 4096) + (wr * 64 + fr) * 32 + swz;

  f32x4 acc[4][4] = {};
  if (diag) gram_main<2>(Xb, ga0, ga1, gb0, gb1, &lds[0][0], tid, aoff, boff, acc);
  else      gram_main<4>(Xb, ga0, ga1, gb0, gb1, &lds[0][0], tid, aoff, boff, acc);

  // Epilogue. C/D map: col = lane&15, row = (lane>>4)*4 + reg.
  const int jc = colBase + wc * 64 + fr;
  float aj[4], dj[4];
  #pragma unroll
  for (int ni = 0; ni < 4; ++ni) {
    aj[ni] = amu [b*N_ + jc + ni*16];
    dj[ni] = invd[b*N_ + jc + ni*16];
  }
  #pragma unroll
  for (int mi = 0; mi < 4; ++mi) {
    const int ibase = rowBase + wr*64 + mi*16 + kc*4;
    float ai[4], di[4];
    #pragma unroll
    for (int r = 0; r < 4; ++r) {
      ai[r] = amu [b*N_ + ibase + r];
      di[r] = invd[b*N_ + ibase + r];
    }
    #pragma unroll
    for (int ni = 0; ni < 4; ++ni) {
      f32x4 g;
      #pragma unroll
      for (int r = 0; r < 4; ++r) {
        float v = (acc[mi][ni][r] - ai[r]*aj[ni]) * (di[r]*dj[ni]);
        g[r] = fminf(fmaxf(v, -1.f), 1.f);
      }
      const int J = jc + ni * 16;
      #pragma unroll
      for (int r = 0; r < 4; ++r)
        out[((size_t)b*N_ + ibase + r)*N_ + J] = g[r];       // tile (ip,jp)
      if (!diag)
        *(f32x4*)&out[((size_t)b*N_ + J)*N_ + ibase] = g;    // mirror (jp,ip)
    }
  }
}

extern "C" void kernel_launch(void* const* d_in, const int* in_sizes, int n_in,
                              void* d_out, int out_size, void* d_ws, size_t ws_size,
                              hipStream_t stream) {
  const float* X = (const float*)d_in[0];
  // bn_weight / bn_bias provably cancel in the correlation output.
  float* out = (float*)d_out;

  char* ws = (char*)d_ws;
  short* XbT  = (short*)ws;                      // 64 MiB bf16 (N,T)
  size_t off  = (size_t)B_ * N_ * T_ * sizeof(short);
  float* amu  = (float*)(ws + off);              // 128 KiB
  float* invd = amu + B_ * N_;                   // 128 KiB

  k_prep<<<dim3(N_/64, B_), 256, 0, stream>>>(X, XbT, amu, invd);
  k_gram<<<dim3(64 * 10), 256, 0, stream>>>(XbT, amu, invd, out);
}